// Round 1
// baseline (386.938 us; speedup 1.0000x reference)
//
#include <hip/hip_runtime.h>
#include <hip/hip_bf16.h>

// SkipGRU: B=64, T=4096, F=128, U=128, P=16  ->  1024 chains of length 256.
// One workgroup per batch (64 WGs), 16 chains (= skip phases) per WG.
// 12 waves * 32 output-cols; weights register-resident as fp16 MFMA B-frags.

#define B_N 64
#define T_N 4096
#define F_N 128
#define U_N 128
#define P_N 16
#define L_N 256
#define NW 12
#define NT (NW * 64)   // 768 threads

typedef _Float16 f16x8 __attribute__((ext_vector_type(8)));
typedef float f32x4 __attribute__((ext_vector_type(4)));

__device__ __forceinline__ float sigmoidf_(float x) {
    return __builtin_amdgcn_rcpf(1.0f + __expf(-x));
}

// Fragment k-mapping (consistent for A and B so any HW k-permutation cancels):
// k_in_tile = (e>>2)*16 + (lane>>4)*4 + (e&3)
// Inverse: given kk in [0,32): e = ((kk>>4)<<2)|(kk&3), lane_group = (kk>>2)&3
__device__ __forceinline__ int frag_idx(int m, int f) {
    int kt = f >> 5, kk = f & 31;
    int e = ((kk >> 4) << 2) | (kk & 3);
    int lw = m | (((kk >> 2) & 3) << 4);
    return kt * 512 + lw * 8 + e;   // element index into [4][64][8] fp16
}

__global__ __launch_bounds__(NT, 1) void skipgru_kernel(
    const float* __restrict__ xg, const float* __restrict__ Wk,
    const float* __restrict__ Wr, const float* __restrict__ bias,
    float* __restrict__ out)
{
    __shared__ __align__(16) _Float16 A_x[2][2048];  // [buf][ktile*512+lane*8+e]
    __shared__ __align__(16) _Float16 A_h[2048];
    __shared__ float stage_zr[16][260];   // 260 % 8 == 4 -> 2-way (free) banks
    __shared__ float stage_xh[16][132];
    __shared__ float stage_hh[16][132];
    __shared__ float h_st[16][128];
    __shared__ float bz[128], br[128], bxh[128], brh[128];

    const int tid  = threadIdx.x;
    const int lane = tid & 63;
    const int wave = tid >> 6;
    const int b    = blockIdx.x;

    // --- biases: bz = b_in_z + b_rec_z, br likewise; h-gate biases kept split
    if (tid < 512) {
        int u = tid & 127, w = tid >> 7;
        if (w == 0)      bz[u]  = bias[u]       + bias[384 + u];
        else if (w == 1) br[u]  = bias[128 + u] + bias[384 + 128 + u];
        else if (w == 2) bxh[u] = bias[256 + u];
        else             brh[u] = bias[384 + 256 + u];
    }
    // --- zero h state & A_h, load x for step 0 into fragment layout
    for (int q = tid; q < 2048; q += NT) {
        ((float*)h_st)[q] = 0.0f;
        A_h[q] = (_Float16)0.0f;
        int m = q >> 7, f = q & 127;
        float v = xg[((size_t)b * T_N + m) * F_N + f];
        A_x[0][frag_idx(m, f)] = (_Float16)v;
    }

    // --- load weight fragments into registers (once; amortized over 256 steps)
    f16x8 wkf[2][4], wrf[2][4];
    {
        int nl = lane & 15, lg = lane >> 4;
        #pragma unroll
        for (int nt = 0; nt < 2; ++nt) {
            int n = wave * 32 + nt * 16 + nl;
            #pragma unroll
            for (int kt = 0; kt < 4; ++kt) {
                #pragma unroll
                for (int e = 0; e < 8; ++e) {
                    int k = kt * 32 + ((e >> 2) << 4) + (lg << 2) + (e & 3);
                    wkf[nt][kt][e] = (_Float16)Wk[k * 384 + n];
                    wrf[nt][kt][e] = (_Float16)Wr[k * 384 + n];
                }
            }
        }
    }
    __syncthreads();

    for (int l = 0; l < L_N; ++l) {
        // --- prefetch x for step l+1 into registers (fixed 3-slot, no scratch)
        float xv0 = 0.f, xv1 = 0.f, xv2 = 0.f;
        if (l + 1 < L_N) {
            size_t base = ((size_t)b * T_N + (size_t)(l + 1) * P_N) * F_N;
            xv0 = xg[base + tid];
            xv1 = xg[base + tid + 768];
            if (tid < 512) xv2 = xg[base + tid + 1536];
        }

        // --- MFMA phase: xm = x*Wk, hm = h*Wr (fp32 accum)
        const f16x8* Axp = (const f16x8*)&A_x[l & 1][0];
        const f16x8* Ahp = (const f16x8*)&A_h[0];
        f16x8 ax[4], ah[4];
        #pragma unroll
        for (int kt = 0; kt < 4; ++kt) {
            ax[kt] = Axp[kt * 64 + lane];
            ah[kt] = Ahp[kt * 64 + lane];
        }
        f32x4 accx[2], acch[2];
        #pragma unroll
        for (int nt = 0; nt < 2; ++nt) {
            #pragma unroll
            for (int e = 0; e < 4; ++e) { accx[nt][e] = 0.f; acch[nt][e] = 0.f; }
            #pragma unroll
            for (int kt = 0; kt < 4; ++kt) {
                accx[nt] = __builtin_amdgcn_mfma_f32_16x16x32_f16(ax[kt], wkf[nt][kt], accx[nt], 0, 0, 0);
                acch[nt] = __builtin_amdgcn_mfma_f32_16x16x32_f16(ah[kt], wrf[nt][kt], acch[nt], 0, 0, 0);
            }
        }

        // --- store prefetched x into the other A_x buffer
        if (l + 1 < L_N) {
            int buf = (l + 1) & 1;
            A_x[buf][frag_idx(tid >> 7, tid & 127)] = (_Float16)xv0;
            int q1 = tid + 768;
            A_x[buf][frag_idx(q1 >> 7, q1 & 127)] = (_Float16)xv1;
            if (tid < 512) {
                int q2 = tid + 1536;
                A_x[buf][frag_idx(q2 >> 7, q2 & 127)] = (_Float16)xv2;
            }
        }

        // --- stage accumulators to LDS (C/D layout: col=lane&15, row=4*(lane>>4)+e)
        #pragma unroll
        for (int nt = 0; nt < 2; ++nt) {
            int n  = wave * 32 + nt * 16 + (lane & 15);
            int m0 = (lane >> 4) << 2;
            if (n < 256) {   // z and r blocks: xm+hm can be pre-summed
                #pragma unroll
                for (int e = 0; e < 4; ++e)
                    stage_zr[m0 + e][n] = accx[nt][e] + acch[nt][e];
            } else {         // h block: reset_after=True needs xm_h, hm_h separate
                #pragma unroll
                for (int e = 0; e < 4; ++e) {
                    stage_xh[m0 + e][n - 256] = accx[nt][e];
                    stage_hh[m0 + e][n - 256] = acch[nt][e];
                }
            }
        }
        __syncthreads();

        // --- gate phase (fp32): 2048 elements over 768 threads
        for (int q = tid; q < 2048; q += NT) {
            int m = q >> 7, u = q & 127;
            float z  = sigmoidf_(stage_zr[m][u] + bz[u]);
            float r  = sigmoidf_(stage_zr[m][128 + u] + br[u]);
            float hh = fmaxf(0.0f, stage_xh[m][u] + bxh[u] + r * (stage_hh[m][u] + brh[u]));
            float hold = h_st[m][u];
            float hn = z * hold + (1.0f - z) * hh;
            h_st[m][u] = hn;
            out[((size_t)b * T_N + (size_t)l * P_N + m) * U_N + u] = hn;
            A_h[frag_idx(m, u)] = (_Float16)hn;   // next step's A operand
        }
        __syncthreads();
    }
}

extern "C" void kernel_launch(void* const* d_in, const int* in_sizes, int n_in,
                              void* d_out, int out_size, void* d_ws, size_t ws_size,
                              hipStream_t stream) {
    const float* inputs = (const float*)d_in[0];
    const float* kernel = (const float*)d_in[1];
    const float* rker   = (const float*)d_in[2];
    const float* bias   = (const float*)d_in[3];
    float* o = (float*)d_out;
    hipLaunchKernelGGL(skipgru_kernel, dim3(B_N), dim3(NT), 0, stream,
                       inputs, kernel, rker, bias, o);
}

// Round 2
// 282.922 us; speedup vs baseline: 1.3677x; 1.3677x over previous
//
#include <hip/hip_runtime.h>
#include <hip/hip_bf16.h>

// SkipGRU: B=64, T=4096, F=128, U=128, P=16 -> 1024 chains of length 256.
// 64 WGs (one per batch), 16 chains/WG, 12 waves. Weights register-resident
// as fp16 MFMA B-frags. Raw s_barrier (lgkmcnt only, never vmcnt) so the
// x-prefetch and out-stores stay in flight across barriers.

#define B_N 64
#define T_N 4096
#define F_N 128
#define U_N 128
#define P_N 16
#define L_N 256
#define NW 12
#define NT (NW * 64)   // 768 threads

typedef _Float16 f16x8 __attribute__((ext_vector_type(8)));
typedef _Float16 f16x4 __attribute__((ext_vector_type(4)));
typedef float f32x4 __attribute__((ext_vector_type(4)));

__device__ __forceinline__ float sigmoidf_(float x) {
    return __builtin_amdgcn_rcpf(1.0f + __expf(-x));
}

// Fragment k-mapping (same permutation for A and B so HW k-order cancels):
// k_in_tile = (e>>2)*16 + (lane>>4)*4 + (e&3)
// Quad (m, u0) with u0%4==0 -> 4 consecutive f16 elements (one 8B run).
__device__ __forceinline__ int frag_q(int m, int u0) {
    int kt = u0 >> 5, lg = (u0 >> 2) & 3, hi = (u0 >> 4) & 1;
    return kt * 512 + ((m | (lg << 4)) << 3) + (hi << 2);
}

// barrier with LDS-only drain; global loads/stores stay in flight
#define BAR() do { \
    asm volatile("s_waitcnt lgkmcnt(0)" ::: "memory"); \
    __builtin_amdgcn_s_barrier(); \
    __builtin_amdgcn_sched_barrier(0); \
} while (0)

__global__ __launch_bounds__(NT, 1) void skipgru_kernel(
    const float* __restrict__ xg, const float* __restrict__ Wk,
    const float* __restrict__ Wr, const float* __restrict__ bias,
    float* __restrict__ out)
{
    __shared__ __align__(16) _Float16 A_x[2][2048];  // [buf][kt*512 + lane*8 + e]
    __shared__ __align__(16) _Float16 A_h[2048];
    __shared__ __align__(16) float stage_zr[16][260]; // z|r pre-acts (xm+hm fused)
    __shared__ __align__(16) float stage_xh[16][132]; // h-block xm
    __shared__ __align__(16) float stage_hh[16][132]; // h-block hm
    __shared__ __align__(16) float h_st[16][132];
    __shared__ __align__(16) float bz[128], br_[128], bxh[128], brh[128];

    const int tid  = threadIdx.x;
    const int lane = tid & 63;
    const int wave = tid >> 6;
    const int b    = blockIdx.x;
    const int gm   = tid & 15;          // gate-phase row (tid<512)
    const int u0   = (tid >> 4) << 2;   // gate-phase u-quad base (0..124)

    // --- biases: z/r get input+recurrent pre-summed; h-gate kept split
    if (tid < 512) {
        int u = tid & 127, w = tid >> 7;
        if (w == 0)      bz[u]  = bias[u]       + bias[384 + u];
        else if (w == 1) br_[u] = bias[128 + u] + bias[384 + 128 + u];
        else if (w == 2) bxh[u] = bias[256 + u];
        else             brh[u] = bias[384 + 256 + u];
    }
    for (int q = tid; q < 2048; q += NT) A_h[q] = (_Float16)0.0f;
    for (int q = tid; q < 16 * 132; q += NT) ((float*)h_st)[q] = 0.0f;

    // --- weights -> registers (once; amortized over 256 steps)
    f16x8 wkf[2][4], wrf[2][4];
    {
        int nl = lane & 15, lg = lane >> 4;
        #pragma unroll
        for (int nt = 0; nt < 2; ++nt) {
            int n = wave * 32 + nt * 16 + nl;
            #pragma unroll
            for (int kt = 0; kt < 4; ++kt) {
                #pragma unroll
                for (int e = 0; e < 8; ++e) {
                    int k = kt * 32 + ((e >> 2) << 4) + (lg << 2) + (e & 3);
                    wkf[nt][kt][e] = (_Float16)Wk[k * 384 + n];
                    wrf[nt][kt][e] = (_Float16)Wr[k * 384 + n];
                }
            }
        }
    }

    // --- x pipeline prologue: A_x[0] <- L(0); xsB=L(1); xsA=L(2)
    const float* xb = xg + (size_t)b * T_N * F_N;
    float4 xsA = {0, 0, 0, 0}, xsB = {0, 0, 0, 0};
    if (tid < 512) {
        xsA = *(const float4*)(xb + (size_t)gm * F_N + u0);
        xsB = *(const float4*)(xb + (size_t)(P_N + gm) * F_N + u0);
        f16x4 v; v[0] = (_Float16)xsA.x; v[1] = (_Float16)xsA.y;
                 v[2] = (_Float16)xsA.z; v[3] = (_Float16)xsA.w;
        *(f16x4*)&A_x[0][frag_q(gm, u0)] = v;
        xsA = *(const float4*)(xb + (size_t)(2 * P_N + gm) * F_N + u0);
    }
    __syncthreads();   // one-time full drain is fine here

    auto step = [&](int l, float4& xs) {
        // ---- MFMA phase
        const f16x8* Axp = (const f16x8*)&A_x[l & 1][0];
        const f16x8* Ahp = (const f16x8*)&A_h[0];
        f16x8 ax[4], ah[4];
        #pragma unroll
        for (int kt = 0; kt < 4; ++kt) {
            ax[kt] = Axp[kt * 64 + lane];
            ah[kt] = Ahp[kt * 64 + lane];
        }
        if (wave < 8) {   // z/r blocks: xm+hm fused in one accumulator
            f32x4 acc[2];
            #pragma unroll
            for (int nt = 0; nt < 2; ++nt) {
                #pragma unroll
                for (int e = 0; e < 4; ++e) acc[nt][e] = 0.f;
                #pragma unroll
                for (int kt = 0; kt < 4; ++kt) {
                    acc[nt] = __builtin_amdgcn_mfma_f32_16x16x32_f16(ax[kt], wkf[nt][kt], acc[nt], 0, 0, 0);
                    acc[nt] = __builtin_amdgcn_mfma_f32_16x16x32_f16(ah[kt], wrf[nt][kt], acc[nt], 0, 0, 0);
                }
            }
            #pragma unroll
            for (int nt = 0; nt < 2; ++nt) {
                int n = wave * 32 + nt * 16 + (lane & 15), m0 = (lane >> 4) << 2;
                #pragma unroll
                for (int e = 0; e < 4; ++e) stage_zr[m0 + e][n] = acc[nt][e];
            }
        } else {          // h block: reset_after=True needs xm_h, hm_h separate
            f32x4 accx[2], acch[2];
            #pragma unroll
            for (int nt = 0; nt < 2; ++nt) {
                #pragma unroll
                for (int e = 0; e < 4; ++e) { accx[nt][e] = 0.f; acch[nt][e] = 0.f; }
                #pragma unroll
                for (int kt = 0; kt < 4; ++kt) {
                    accx[nt] = __builtin_amdgcn_mfma_f32_16x16x32_f16(ax[kt], wkf[nt][kt], accx[nt], 0, 0, 0);
                    acch[nt] = __builtin_amdgcn_mfma_f32_16x16x32_f16(ah[kt], wrf[nt][kt], acch[nt], 0, 0, 0);
                }
            }
            #pragma unroll
            for (int nt = 0; nt < 2; ++nt) {
                int n = wave * 32 + nt * 16 + (lane & 15) - 256, m0 = (lane >> 4) << 2;
                #pragma unroll
                for (int e = 0; e < 4; ++e) {
                    stage_xh[m0 + e][n] = accx[nt][e];
                    stage_hh[m0 + e][n] = acch[nt][e];
                }
            }
        }
        BAR();

        // ---- gate phase: 512 threads, one (m, u-quad) each
        if (tid < 512) {
            float4 xz = *(const float4*)&stage_zr[gm][u0];
            float4 xr = *(const float4*)&stage_zr[gm][128 + u0];
            float4 xh = *(const float4*)&stage_xh[gm][u0];
            float4 hh = *(const float4*)&stage_hh[gm][u0];
            float4 bzv = *(const float4*)&bz[u0];
            float4 brv = *(const float4*)&br_[u0];
            float4 bxv = *(const float4*)&bxh[u0];
            float4 bhv = *(const float4*)&brh[u0];
            float4 h  = *(float4*)&h_st[gm][u0];
            float4 hn;
            {
                float z, r, c;
                z = sigmoidf_(xz.x + bzv.x); r = sigmoidf_(xr.x + brv.x);
                c = fmaxf(0.f, xh.x + bxv.x + r * (hh.x + bhv.x));
                hn.x = z * h.x + (1.f - z) * c;
                z = sigmoidf_(xz.y + bzv.y); r = sigmoidf_(xr.y + brv.y);
                c = fmaxf(0.f, xh.y + bxv.y + r * (hh.y + bhv.y));
                hn.y = z * h.y + (1.f - z) * c;
                z = sigmoidf_(xz.z + bzv.z); r = sigmoidf_(xr.z + brv.z);
                c = fmaxf(0.f, xh.z + bxv.z + r * (hh.z + bhv.z));
                hn.z = z * h.z + (1.f - z) * c;
                z = sigmoidf_(xz.w + bzv.w); r = sigmoidf_(xr.w + brv.w);
                c = fmaxf(0.f, xh.w + bxv.w + r * (hh.w + bhv.w));
                hn.w = z * h.w + (1.f - z) * c;
            }
            *(float4*)&h_st[gm][u0] = hn;
            *(float4*)(out + ((size_t)b * T_N + (size_t)l * P_N + gm) * U_N + u0) = hn;
            f16x4 hv; hv[0] = (_Float16)hn.x; hv[1] = (_Float16)hn.y;
                      hv[2] = (_Float16)hn.z; hv[3] = (_Float16)hn.w;
            *(f16x4*)&A_h[frag_q(gm, u0)] = hv;

            // consume L(l+1) -> A_x[(l+1)&1]; issue L(l+3) into same reg set
            if (l + 1 < L_N) {
                f16x4 xv; xv[0] = (_Float16)xs.x; xv[1] = (_Float16)xs.y;
                          xv[2] = (_Float16)xs.z; xv[3] = (_Float16)xs.w;
                *(f16x4*)&A_x[(l + 1) & 1][frag_q(gm, u0)] = xv;
                int t = l + 3;
                if (t < L_N)
                    xs = *(const float4*)(xb + (size_t)(t * P_N + gm) * F_N + u0);
            }
        }
        BAR();
    };

    for (int l = 0; l < L_N; l += 2) {
        step(l, xsB);       // even l consumes xsB (holds L(l+1))
        step(l + 1, xsA);   // odd  l consumes xsA
    }
}

extern "C" void kernel_launch(void* const* d_in, const int* in_sizes, int n_in,
                              void* d_out, int out_size, void* d_ws, size_t ws_size,
                              hipStream_t stream) {
    const float* inputs = (const float*)d_in[0];
    const float* kernel = (const float*)d_in[1];
    const float* rker   = (const float*)d_in[2];
    const float* bias   = (const float*)d_in[3];
    float* o = (float*)d_out;
    hipLaunchKernelGGL(skipgru_kernel, dim3(B_N), dim3(NT), 0, stream,
                       inputs, kernel, rker, bias, o);
}

// Round 3
// 204.278 us; speedup vs baseline: 1.8942x; 1.3850x over previous
//
#include <hip/hip_runtime.h>
#include <hip/hip_bf16.h>

// SkipGRU: B=64, T=4096, F=128, U=128, P=16 -> 1024 chains of length 256.
// 64 WGs (one per batch), 16 chains/WG, 8 waves. Each wave owns a 16-col
// u-slice of ALL THREE gate blocks (z,r,h), so gates + h-state live entirely
// in registers: one barrier and one LDS round-trip (the A operands) per step.

#define B_N 64
#define T_N 4096
#define F_N 128
#define U_N 128
#define P_N 16
#define L_N 256
#define NW 8
#define NT (NW * 64)   // 512 threads

typedef _Float16 f16x8 __attribute__((ext_vector_type(8)));
typedef _Float16 f16x4 __attribute__((ext_vector_type(4)));
typedef float f32x4 __attribute__((ext_vector_type(4)));

__device__ __forceinline__ float sigmoidf_(float x) {
    return __builtin_amdgcn_rcpf(1.0f + __expf(-x));
}

// barrier with LDS-only drain; global loads/stores stay in flight
#define BAR() do { \
    asm volatile("s_waitcnt lgkmcnt(0)" ::: "memory"); \
    __builtin_amdgcn_s_barrier(); \
    __builtin_amdgcn_sched_barrier(0); \
} while (0)

__global__ __launch_bounds__(NT, 2) void skipgru_kernel(
    const float* __restrict__ xg, const float* __restrict__ Wk,
    const float* __restrict__ Wr, const float* __restrict__ bias,
    float* __restrict__ out)
{
    // A operands, row-major [m][k], row stride 132 f16 = 264 B (8B-aligned).
    __shared__ __align__(16) _Float16 A_x[2][16][132];
    __shared__ __align__(16) _Float16 A_h[2][16][132];

    const int tid  = threadIdx.x;
    const int lane = tid & 63;
    const int wave = tid >> 6;
    const int ln   = lane & 15;     // A-row / B-col / C-col index
    const int lg   = lane >> 4;     // k-group (A/B), row-group (C/D)
    const int u    = wave * 16 + ln; // this lane's output column
    const int m0   = lg * 4;         // this lane's C/D row base
    const int b    = blockIdx.x;

    // --- per-lane bias scalars (z/r pre-summed input+recurrent)
    const float bz  = bias[u]       + bias[384 + u];
    const float br  = bias[128 + u] + bias[384 + 128 + u];
    const float bxh = bias[256 + u];
    const float brh = bias[384 + 256 + u];

    // --- weight fragments: 6 B-frag sets (z/r/h x Wk/Wr), k-map shared with A
    f16x8 wzk[4], wzr[4], wrk[4], wrr[4], whk[4], whr[4];
    #pragma unroll
    for (int kt = 0; kt < 4; ++kt) {
        #pragma unroll
        for (int e = 0; e < 8; ++e) {
            int k = kt * 32 + ((e >> 2) << 4) + (lg << 2) + (e & 3);
            const float* wkp = Wk + (size_t)k * 384;
            const float* wrp = Wr + (size_t)k * 384;
            wzk[kt][e] = (_Float16)wkp[u];
            wzr[kt][e] = (_Float16)wrp[u];
            wrk[kt][e] = (_Float16)wkp[128 + u];
            wrr[kt][e] = (_Float16)wrp[128 + u];
            whk[kt][e] = (_Float16)wkp[256 + u];
            whr[kt][e] = (_Float16)wrp[256 + u];
        }
    }

    // --- zero A_h[0] (h(-P) = 0)
    for (int q = tid; q < 16 * 132; q += NT) ((_Float16*)A_h[0])[q] = (_Float16)0;

    // --- x staging: thread -> (row sm, col-quad sc); one float4/thread/step
    const int sm = tid & 15, sc = (tid >> 4) << 2;
    const float* xb = xg + (size_t)b * T_N * F_N;
    {
        float4 x0 = *(const float4*)(xb + (size_t)sm * F_N + sc);
        f16x4 v = {(_Float16)x0.x, (_Float16)x0.y, (_Float16)x0.z, (_Float16)x0.w};
        *(f16x4*)&A_x[0][sm][sc] = v;
    }
    float4 xsB = *(const float4*)(xb + (size_t)(P_N + sm) * F_N + sc);      // L(1)
    float4 xsA = *(const float4*)(xb + (size_t)(2 * P_N + sm) * F_N + sc);  // L(2)

    f32x4 hreg = {0.f, 0.f, 0.f, 0.f};   // h for rows m0..m0+3 at col u
    __syncthreads();

    auto step = [&](int l, float4& xs) {
        const int cur = l & 1, nxt = (l + 1) & 1;
        // ---- A-fragment reads: two b64 per ktile (k = kt*32+4lg+{0..3,16..19})
        f16x8 axf[4], ahf[4];
        #pragma unroll
        for (int kt = 0; kt < 4; ++kt) {
            f16x4 lo = *(const f16x4*)&A_x[cur][ln][kt * 32 + 4 * lg];
            f16x4 hi = *(const f16x4*)&A_x[cur][ln][kt * 32 + 4 * lg + 16];
            axf[kt] = __builtin_shufflevector(lo, hi, 0, 1, 2, 3, 4, 5, 6, 7);
            f16x4 lo2 = *(const f16x4*)&A_h[cur][ln][kt * 32 + 4 * lg];
            f16x4 hi2 = *(const f16x4*)&A_h[cur][ln][kt * 32 + 4 * lg + 16];
            ahf[kt] = __builtin_shufflevector(lo2, hi2, 0, 1, 2, 3, 4, 5, 6, 7);
        }
        // ---- 24 MFMAs: 6 independent accumulator chains of 4
        f32x4 azx = {bz, bz, bz, bz}, azh = {0.f, 0.f, 0.f, 0.f};
        f32x4 arx = {br, br, br, br}, arh = {0.f, 0.f, 0.f, 0.f};
        f32x4 axh = {bxh, bxh, bxh, bxh}, ahh = {brh, brh, brh, brh};
        #pragma unroll
        for (int kt = 0; kt < 4; ++kt) {
            azx = __builtin_amdgcn_mfma_f32_16x16x32_f16(axf[kt], wzk[kt], azx, 0, 0, 0);
            arx = __builtin_amdgcn_mfma_f32_16x16x32_f16(axf[kt], wrk[kt], arx, 0, 0, 0);
            axh = __builtin_amdgcn_mfma_f32_16x16x32_f16(axf[kt], whk[kt], axh, 0, 0, 0);
            azh = __builtin_amdgcn_mfma_f32_16x16x32_f16(ahf[kt], wzr[kt], azh, 0, 0, 0);
            arh = __builtin_amdgcn_mfma_f32_16x16x32_f16(ahf[kt], wrr[kt], arh, 0, 0, 0);
            ahh = __builtin_amdgcn_mfma_f32_16x16x32_f16(ahf[kt], whr[kt], ahh, 0, 0, 0);
        }
        // ---- gates fully in-register; h never leaves the lane
        float* op = out + ((size_t)b * T_N + (size_t)l * P_N + m0) * U_N + u;
        #pragma unroll
        for (int e = 0; e < 4; ++e) {
            float z = sigmoidf_(azx[e] + azh[e]);
            float r = sigmoidf_(arx[e] + arh[e]);
            float c = fmaxf(0.f, axh[e] + r * ahh[e]);
            float hn = z * hreg[e] + (1.f - z) * c;
            hreg[e] = hn;
            A_h[nxt][m0 + e][u] = (_Float16)hn;         // transpose write (b16)
            op[(size_t)e * U_N] = hn;                    // global, fire-and-forget
        }
        // ---- x staging: consume L(l+1), issue L(l+3)
        if (l + 1 < L_N) {
            f16x4 v = {(_Float16)xs.x, (_Float16)xs.y, (_Float16)xs.z, (_Float16)xs.w};
            *(f16x4*)&A_x[nxt][sm][sc] = v;
            int t = l + 3;
            if (t < L_N)
                xs = *(const float4*)(xb + (size_t)(t * P_N + sm) * F_N + sc);
        }
        BAR();
    };

    for (int l = 0; l < L_N; l += 2) {
        step(l, xsB);       // even l consumes xsB (holds L(l+1))
        step(l + 1, xsA);   // odd  l consumes xsA
    }
}

extern "C" void kernel_launch(void* const* d_in, const int* in_sizes, int n_in,
                              void* d_out, int out_size, void* d_ws, size_t ws_size,
                              hipStream_t stream) {
    const float* inputs = (const float*)d_in[0];
    const float* kernel = (const float*)d_in[1];
    const float* rker   = (const float*)d_in[2];
    const float* bias   = (const float*)d_in[3];
    float* o = (float*)d_out;
    hipLaunchKernelGGL(skipgru_kernel, dim3(B_N), dim3(NT), 0, stream,
                       inputs, kernel, rker, bias, o);
}

// Round 4
// 186.528 us; speedup vs baseline: 2.0744x; 1.0952x over previous
//
#include <hip/hip_runtime.h>
#include <hip/hip_bf16.h>

// SkipGRU: B=64, T=4096, F=128, U=128, P=16 -> 1024 chains of length 256.
// 64 WGs (one per batch), 16 chains/WG, 8 waves; each wave owns one 16-col
// u-slice of all three gates (z,r,h) so gates + h-state stay in registers.
// Software-pipelined: x-MFMAs for step l+1 run in the shadow of step l's
// h-MFMA chain, accumulating into a ping-pong acc set (bias pre-folded).
// A operands live in LDS in fragment-contiguous layout -> 1 ds_read_b128/kt.

#define B_N 64
#define T_N 4096
#define F_N 128
#define U_N 128
#define P_N 16
#define L_N 256
#define NW 8
#define NT (NW * 64)   // 512 threads

typedef _Float16 f16x8 __attribute__((ext_vector_type(8)));
typedef _Float16 f16x4 __attribute__((ext_vector_type(4)));
typedef float f32x4 __attribute__((ext_vector_type(4)));

__device__ __forceinline__ float sigmoidf_(float x) {
    return __builtin_amdgcn_rcpf(1.0f + __expf(-x));
}

// Position of logical k within a fragment-contiguous row:
// row[kt*32 + lg*8 + e] holds k = kt*32 + 16*(e>>2) + 4*lg + (e&3).
__device__ __forceinline__ int fpos(int k) {
    return ((k >> 5) << 5) + (((k >> 2) & 3) << 3) + (((k >> 4) & 1) << 2) + (k & 3);
}

// barrier with LDS-only drain; global loads/stores stay in flight
#define BAR() do { \
    asm volatile("s_waitcnt lgkmcnt(0)" ::: "memory"); \
    __builtin_amdgcn_s_barrier(); \
    __builtin_amdgcn_sched_barrier(0); \
} while (0)

struct Acc { f32x4 z, r, xh, hh; };

__global__ __launch_bounds__(NT, 2) void skipgru_kernel(
    const float* __restrict__ xg, const float* __restrict__ Wk,
    const float* __restrict__ Wr, const float* __restrict__ bias,
    float* __restrict__ out)
{
    // Fragment-contiguous A operands, padded row (132 f16 = 264 B) for banks.
    __shared__ __align__(16) _Float16 A_x[2][16][132];
    __shared__ __align__(16) _Float16 A_h[2][16][132];

    const int tid  = threadIdx.x;
    const int lane = tid & 63;
    const int wave = tid >> 6;
    const int ln   = lane & 15;      // A-row / C-col index
    const int lg   = lane >> 4;      // k-group (A/B), row-group (C/D)
    const int u    = wave * 16 + ln; // this lane's output column
    const int m0   = lg * 4;         // this lane's C/D row base
    const int b    = blockIdx.x;
    const int hcol = fpos(u);        // A_h transpose-write column

    // --- per-lane bias scalars (z/r pre-summed input+recurrent)
    const float bz  = bias[u]       + bias[384 + u];
    const float br  = bias[128 + u] + bias[384 + 128 + u];
    const float bxh = bias[256 + u];
    const float brh = bias[384 + 256 + u];

    // --- weight fragments: 6 B-frag sets (z/r/h x Wk/Wr), k-map = fpos inverse
    f16x8 wzk[4], wzr[4], wrk[4], wrr[4], whk[4], whr[4];
    #pragma unroll
    for (int kt = 0; kt < 4; ++kt) {
        #pragma unroll
        for (int e = 0; e < 8; ++e) {
            int k = kt * 32 + ((e >> 2) << 4) + (lg << 2) + (e & 3);
            const float* wkp = Wk + (size_t)k * 384;
            const float* wrp = Wr + (size_t)k * 384;
            wzk[kt][e] = (_Float16)wkp[u];
            wzr[kt][e] = (_Float16)wrp[u];
            wrk[kt][e] = (_Float16)wkp[128 + u];
            wrr[kt][e] = (_Float16)wrp[128 + u];
            whk[kt][e] = (_Float16)wkp[256 + u];
            whr[kt][e] = (_Float16)wrp[256 + u];
        }
    }

    // --- zero A_h[0] (h(-P) = 0)
    for (int q = tid; q < 16 * 132; q += NT) ((_Float16*)A_h[0])[q] = (_Float16)0;

    // --- x staging map: thread -> (row sm, col-quad sc); frag-layout position
    const int sm = tid & 15, sc = (tid >> 4) << 2;
    const int scp = fpos(sc);        // sc%4==0 -> 4 consecutive frag slots
    const float* xb = xg + (size_t)b * T_N * F_N;
    {
        float4 x0 = *(const float4*)(xb + (size_t)sm * F_N + sc);
        float4 x1 = *(const float4*)(xb + (size_t)(P_N + sm) * F_N + sc);
        f16x4 v0 = {(_Float16)x0.x, (_Float16)x0.y, (_Float16)x0.z, (_Float16)x0.w};
        f16x4 v1 = {(_Float16)x1.x, (_Float16)x1.y, (_Float16)x1.z, (_Float16)x1.w};
        *(f16x4*)&A_x[0][sm][scp] = v0;
        *(f16x4*)&A_x[1][sm][scp] = v1;
    }
    float4 xsB = *(const float4*)(xb + (size_t)(2 * P_N + sm) * F_N + sc);  // L(2)
    float4 xsA = *(const float4*)(xb + (size_t)(3 * P_N + sm) * F_N + sc);  // L(3)

    f32x4 hreg = {0.f, 0.f, 0.f, 0.f};
    float* op = out + ((size_t)b * T_N + m0) * U_N + u;
    __syncthreads();   // one-time full drain (staging + A_h zero visible)

    // --- prologue: x-part of step 0 into acc set P
    Acc P, Q;
    {
        f16x8 axf[4];
        #pragma unroll
        for (int kt = 0; kt < 4; ++kt)
            axf[kt] = *(const f16x8*)&A_x[0][ln][kt * 32 + lg * 8];
        P.z  = {bz, bz, bz, bz};
        P.r  = {br, br, br, br};
        P.xh = {bxh, bxh, bxh, bxh};
        P.hh = {brh, brh, brh, brh};
        #pragma unroll
        for (int kt = 0; kt < 4; ++kt) {
            P.z  = __builtin_amdgcn_mfma_f32_16x16x32_f16(axf[kt], wzk[kt], P.z, 0, 0, 0);
            P.r  = __builtin_amdgcn_mfma_f32_16x16x32_f16(axf[kt], wrk[kt], P.r, 0, 0, 0);
            P.xh = __builtin_amdgcn_mfma_f32_16x16x32_f16(axf[kt], whk[kt], P.xh, 0, 0, 0);
        }
    }

    auto step = [&](int l, float4& xs, Acc& cur, Acc& nxt) {
        const int rbuf = l & 1, wbuf = (l + 1) & 1;
        // ---- critical path: A_h fragments -> 12 h-MFMAs into cur
        f16x8 ahf[4];
        #pragma unroll
        for (int kt = 0; kt < 4; ++kt)
            ahf[kt] = *(const f16x8*)&A_h[rbuf][ln][kt * 32 + lg * 8];
        #pragma unroll
        for (int kt = 0; kt < 4; ++kt) {
            cur.z  = __builtin_amdgcn_mfma_f32_16x16x32_f16(ahf[kt], wzr[kt], cur.z, 0, 0, 0);
            cur.r  = __builtin_amdgcn_mfma_f32_16x16x32_f16(ahf[kt], wrr[kt], cur.r, 0, 0, 0);
            cur.hh = __builtin_amdgcn_mfma_f32_16x16x32_f16(ahf[kt], whr[kt], cur.hh, 0, 0, 0);
        }
        // ---- independent: x-part of step l+1 into nxt (fills MFMA pipe)
        if (l + 1 < L_N) {
            f16x8 axf[4];
            #pragma unroll
            for (int kt = 0; kt < 4; ++kt)
                axf[kt] = *(const f16x8*)&A_x[wbuf][ln][kt * 32 + lg * 8];
            nxt.z  = {bz, bz, bz, bz};
            nxt.r  = {br, br, br, br};
            nxt.xh = {bxh, bxh, bxh, bxh};
            nxt.hh = {brh, brh, brh, brh};
            #pragma unroll
            for (int kt = 0; kt < 4; ++kt) {
                nxt.z  = __builtin_amdgcn_mfma_f32_16x16x32_f16(axf[kt], wzk[kt], nxt.z, 0, 0, 0);
                nxt.r  = __builtin_amdgcn_mfma_f32_16x16x32_f16(axf[kt], wrk[kt], nxt.r, 0, 0, 0);
                nxt.xh = __builtin_amdgcn_mfma_f32_16x16x32_f16(axf[kt], whk[kt], nxt.xh, 0, 0, 0);
            }
        }
        // ---- gate fully in-register; h never leaves the lane
        #pragma unroll
        for (int e = 0; e < 4; ++e) {
            float z = sigmoidf_(cur.z[e]);
            float r = sigmoidf_(cur.r[e]);
            float c = fmaxf(0.f, fmaf(r, cur.hh[e], cur.xh[e]));
            float hn = fmaf(z, hreg[e] - c, c);
            hreg[e] = hn;
            A_h[wbuf][m0 + e][hcol] = (_Float16)hn;   // transpose write (b16)
            op[(size_t)e * U_N] = hn;                  // global, fire-and-forget
        }
        op += P_N * U_N;
        // ---- stage x(l+2) into A_x[l&1]; prefetch x(l+4)
        if (l + 2 < L_N) {
            f16x4 v = {(_Float16)xs.x, (_Float16)xs.y, (_Float16)xs.z, (_Float16)xs.w};
            *(f16x4*)&A_x[rbuf][sm][scp] = v;
            if (l + 4 < L_N)
                xs = *(const float4*)(xb + (size_t)((l + 4) * P_N + sm) * F_N + sc);
        }
        BAR();
    };

    for (int l = 0; l < L_N; l += 2) {
        step(l, xsB, P, Q);       // even l consumes xsB (holds x(l+2))
        step(l + 1, xsA, Q, P);   // odd  l consumes xsA
    }
}

extern "C" void kernel_launch(void* const* d_in, const int* in_sizes, int n_in,
                              void* d_out, int out_size, void* d_ws, size_t ws_size,
                              hipStream_t stream) {
    const float* inputs = (const float*)d_in[0];
    const float* kernel = (const float*)d_in[1];
    const float* rker   = (const float*)d_in[2];
    const float* bias   = (const float*)d_in[3];
    float* o = (float*)d_out;
    hipLaunchKernelGGL(skipgru_kernel, dim3(B_N), dim3(NT), 0, stream,
                       inputs, kernel, rker, bias, o);
}